// Round 4
// baseline (1910.156 us; speedup 1.0000x reference)
//
#include <hip/hip_runtime.h>
#include <math.h>

#define NODES   325
#define TOPK    8
#define B_SZ    8
#define T_LEN   64
#define EPS     1e-5f
#define NTOK    ((size_t)B_SZ * T_LEN * NODES)   /* 166,400 */

/* ---- LDS layout for opt_mamba (dynamic, floats) ----
   s_h   [64][68]  LN out -> xT tile      4352
   s_xc  [64][132] xi -> xc -> y -> u     8448
   s_dbl [64][40]  x_proj output          2560
   sW    [64][68]  weight chunk (4 in_w halves / 2 out_w c-chunks)  4352
   total 19712 floats = 78848 B  -> 2 blocks/CU (16 waves, 4/SIMD) */
#define HPAD    68
#define XCPAD   132
#define DBLPAD  40
#define WH      68
#define OFF_H   0
#define OFF_XC  4352
#define OFF_DBL 12800
#define OFF_W   15360
#define SMEM_BYTES (19712*4)

__device__ __forceinline__ float waveSum64(float v){
  #pragma unroll
  for(int m=1;m<64;m<<=1) v += __shfl_xor(v, m, 64);
  return v;
}
__device__ __forceinline__ float groupSum16(float v){
  v += __shfl_xor(v, 1, 64);
  v += __shfl_xor(v, 2, 64);
  v += __shfl_xor(v, 4, 64);
  v += __shfl_xor(v, 8, 64);
  return v;
}
__device__ __forceinline__ float dot64(const float* __restrict__ s,
                                       const float* __restrict__ w, float acc){
  #pragma unroll
  for(int q=0;q<64;q++) acc = fmaf(s[q], w[q], acc);
  return acc;
}
__device__ __forceinline__ float4 f4fma(float s, float4 a, float4 acc){
  acc.x = fmaf(s, a.x, acc.x);
  acc.y = fmaf(s, a.y, acc.y);
  acc.z = fmaf(s, a.z, acc.z);
  acc.w = fmaf(s, a.w, acc.w);
  return acc;
}
__device__ __forceinline__ float dp4(float4 a, float4 b, float acc){
  acc = fmaf(a.x, b.x, acc);
  acc = fmaf(a.y, b.y, acc);
  acc = fmaf(a.z, b.z, acc);
  acc = fmaf(a.w, b.w, acc);
  return acc;
}

// ---------------- Mamba + fused K/V/gate tail (R10) ----------------
// grid = B*NODES blocks, 512 threads, 78.8 KB LDS -> 2 blocks/CU.
__global__ __launch_bounds__(512)
void opt_mamba(const float* __restrict__ x,
               const float* __restrict__ ln1_g, const float* __restrict__ ln1_b,
               const float* __restrict__ in_w,
               const float* __restrict__ conv_w, const float* __restrict__ conv_b,
               const float* __restrict__ xp_w,
               const float* __restrict__ dt_w, const float* __restrict__ dt_b,
               const float* __restrict__ A_log, const float* __restrict__ Dss,
               const float* __restrict__ out_w,
               const float* __restrict__ k_w, const float* __restrict__ k_b,
               const float* __restrict__ v_w, const float* __restrict__ v_b,
               const float* __restrict__ g1_w, const float* __restrict__ g1_b,
               const float* __restrict__ g2_w, const float* __restrict__ g2_b,
               float* __restrict__ xT,
               float* __restrict__ Kb, float* __restrict__ Vb,
               float* __restrict__ gate, int do_tail)
{
  extern __shared__ float sm[];
  float* s_h   = sm + OFF_H;
  float* s_xc  = sm + OFF_XC;
  float* s_dbl = sm + OFF_DBL;
  float* sW    = sm + OFF_W;

  const int bn   = blockIdx.x;
  const int b    = bn / NODES;
  const int n    = bn % NODES;
  const int tid  = threadIdx.x;
  const int lane = tid & 63;
  const int wv   = tid >> 6;

  // tiling A (in_proj halves, u-mult, K/V tail): 4 rows x 2 tokens
  const int rA = (tid & 15) * 4;
  const int tA = (tid >> 4) * 2;

  const float4 z4 = make_float4(0.f,0.f,0.f,0.f);

  // ---- ph0: stage in_w rows 0..63 + LayerNorm all tokens
  for(int idx = tid; idx < 4096; idx += 512){
    int c = idx & 63, rr = idx >> 6;
    sW[c*WH + rr] = in_w[rr*64 + c];
  }
  {
    const float g_ln = ln1_g[lane], b_ln = ln1_b[lane];
    #pragma unroll
    for(int i=0;i<8;i++){
      int t = wv*8 + i;
      size_t tok = (size_t)(b*T_LEN + t)*NODES + n;
      float v   = x[tok*64 + lane];
      float m   = waveSum64(v) * (1.f/64.f);
      float c   = v - m;
      float var = waveSum64(c*c) * (1.f/64.f);
      s_h[t*HPAD + lane] = c * rsqrtf(var + EPS) * g_ln + b_ln;
    }
  }
  __syncthreads();

  // ---- ph1: xi rows 0..63
  {
    float4 a0 = z4, a1 = z4;
    for(int c0=0;c0<64;c0+=4){
      float4 w0 = *(const float4*)&sW[(c0+0)*WH + rA];
      float4 w1 = *(const float4*)&sW[(c0+1)*WH + rA];
      float4 w2 = *(const float4*)&sW[(c0+2)*WH + rA];
      float4 w3 = *(const float4*)&sW[(c0+3)*WH + rA];
      float4 h0 = *(const float4*)&s_h[(tA+0)*HPAD + c0];
      float4 h1 = *(const float4*)&s_h[(tA+1)*HPAD + c0];
      a0 = f4fma(h0.x,w0,a0); a0 = f4fma(h0.y,w1,a0); a0 = f4fma(h0.z,w2,a0); a0 = f4fma(h0.w,w3,a0);
      a1 = f4fma(h1.x,w0,a1); a1 = f4fma(h1.y,w1,a1); a1 = f4fma(h1.z,w2,a1); a1 = f4fma(h1.w,w3,a1);
    }
    *(float4*)&s_xc[(tA+0)*XCPAD + rA] = a0;
    *(float4*)&s_xc[(tA+1)*XCPAD + rA] = a1;
  }
  __syncthreads();
  for(int idx = tid; idx < 4096; idx += 512){     // stage in_w rows 64..127
    int c = idx & 63, rr = idx >> 6;
    sW[c*WH + rr] = in_w[(64+rr)*64 + c];
  }
  __syncthreads();

  // ---- ph3: xi rows 64..127
  {
    float4 a0 = z4, a1 = z4;
    for(int c0=0;c0<64;c0+=4){
      float4 w0 = *(const float4*)&sW[(c0+0)*WH + rA];
      float4 w1 = *(const float4*)&sW[(c0+1)*WH + rA];
      float4 w2 = *(const float4*)&sW[(c0+2)*WH + rA];
      float4 w3 = *(const float4*)&sW[(c0+3)*WH + rA];
      float4 h0 = *(const float4*)&s_h[(tA+0)*HPAD + c0];
      float4 h1 = *(const float4*)&s_h[(tA+1)*HPAD + c0];
      a0 = f4fma(h0.x,w0,a0); a0 = f4fma(h0.y,w1,a0); a0 = f4fma(h0.z,w2,a0); a0 = f4fma(h0.w,w3,a0);
      a1 = f4fma(h1.x,w0,a1); a1 = f4fma(h1.y,w1,a1); a1 = f4fma(h1.z,w2,a1); a1 = f4fma(h1.w,w3,a1);
    }
    *(float4*)&s_xc[(tA+0)*XCPAD + 64 + rA] = a0;
    *(float4*)&s_xc[(tA+1)*XCPAD + 64 + rA] = a1;
  }
  __syncthreads();

  // ---- ph4: causal conv (window 4) + silu, 4 token-quarters; stage z-lo
  {
    const int dd = tid & 127, tg = tid >> 7;
    float p3 = 0.f, p2 = 0.f, p1 = 0.f;
    if(tg){
      int tq = tg*16;
      p3 = s_xc[(tq-3)*XCPAD + dd];
      p2 = s_xc[(tq-2)*XCPAD + dd];
      p1 = s_xc[(tq-1)*XCPAD + dd];
    }
    __syncthreads();
    const float cw0 = conv_w[dd*4+0], cw1 = conv_w[dd*4+1];
    const float cw2 = conv_w[dd*4+2], cw3 = conv_w[dd*4+3];
    const float cb  = conv_b[dd];
    for(int t=tg*16; t<tg*16+16; t++){
      float xi = s_xc[t*XCPAD + dd];
      float v  = cb + cw0*p3 + cw1*p2 + cw2*p1 + cw3*xi;
      p3 = p2; p2 = p1; p1 = xi;
      s_xc[t*XCPAD + dd] = v / (1.f + __expf(-v));
    }
    for(int idx = tid; idx < 4096; idx += 512){   // stage in_w rows 128..191
      int c = idx & 63, rr = idx >> 6;
      sW[c*WH + rr] = in_w[(128+rr)*64 + c];
    }
  }
  __syncthreads();

  // ---- ph5: z rows 0..63 -> zrA
  float4 zrA[2], zrB[2];
  {
    float4 a0 = z4, a1 = z4;
    for(int c0=0;c0<64;c0+=4){
      float4 w0 = *(const float4*)&sW[(c0+0)*WH + rA];
      float4 w1 = *(const float4*)&sW[(c0+1)*WH + rA];
      float4 w2 = *(const float4*)&sW[(c0+2)*WH + rA];
      float4 w3 = *(const float4*)&sW[(c0+3)*WH + rA];
      float4 h0 = *(const float4*)&s_h[(tA+0)*HPAD + c0];
      float4 h1 = *(const float4*)&s_h[(tA+1)*HPAD + c0];
      a0 = f4fma(h0.x,w0,a0); a0 = f4fma(h0.y,w1,a0); a0 = f4fma(h0.z,w2,a0); a0 = f4fma(h0.w,w3,a0);
      a1 = f4fma(h1.x,w0,a1); a1 = f4fma(h1.y,w1,a1); a1 = f4fma(h1.z,w2,a1); a1 = f4fma(h1.w,w3,a1);
    }
    zrA[0] = a0; zrA[1] = a1;
  }
  __syncthreads();
  for(int idx = tid; idx < 4096; idx += 512){     // stage in_w rows 192..255
    int c = idx & 63, rr = idx >> 6;
    sW[c*WH + rr] = in_w[(192+rr)*64 + c];
  }
  __syncthreads();

  // ---- ph7: z rows 64..127 -> zrB
  {
    float4 a0 = z4, a1 = z4;
    for(int c0=0;c0<64;c0+=4){
      float4 w0 = *(const float4*)&sW[(c0+0)*WH + rA];
      float4 w1 = *(const float4*)&sW[(c0+1)*WH + rA];
      float4 w2 = *(const float4*)&sW[(c0+2)*WH + rA];
      float4 w3 = *(const float4*)&sW[(c0+3)*WH + rA];
      float4 h0 = *(const float4*)&s_h[(tA+0)*HPAD + c0];
      float4 h1 = *(const float4*)&s_h[(tA+1)*HPAD + c0];
      a0 = f4fma(h0.x,w0,a0); a0 = f4fma(h0.y,w1,a0); a0 = f4fma(h0.z,w2,a0); a0 = f4fma(h0.w,w3,a0);
      a1 = f4fma(h1.x,w0,a1); a1 = f4fma(h1.y,w1,a1); a1 = f4fma(h1.z,w2,a1); a1 = f4fma(h1.w,w3,a1);
    }
    zrB[0] = a0; zrB[1] = a1;
  }

  // ---- ph8: dbl = xc @ x_proj.T (36 rows over 8 wave-groups, w from global)
  {
    const int td = tid & 63, rg = tid >> 6;
    const int base = rg*5;
    float dacc[5];
    #pragma unroll
    for(int i=0;i<5;i++) dacc[i] = 0.f;
    for(int c0=0;c0<128;c0+=4){
      float4 xc4 = *(const float4*)&s_xc[td*XCPAD + c0];
      #pragma unroll
      for(int i=0;i<5;i++){
        if(base+i < 36){
          float4 w4 = *(const float4*)&xp_w[(base+i)*128 + c0];
          dacc[i] = dp4(xc4, w4, dacc[i]);
        }
      }
    }
    #pragma unroll
    for(int i=0;i<5;i++)
      if(base+i < 36) s_dbl[td*DBLPAD + base + i] = dacc[i];
  }
  __syncthreads();

  // ---- ph9: selective scan, ALL 512 threads: d = tid>>2, s-quartet = tid&3
  {
    const int d  = tid >> 2;
    const int sq = tid & 3;
    float A_d[4], hs[4];
    #pragma unroll
    for(int i=0;i<4;i++){ A_d[i] = -__expf(A_log[d*16 + sq*4 + i]); hs[i] = 0.f; }
    const float dtw0 = dt_w[d*4+0], dtw1 = dt_w[d*4+1];
    const float dtw2 = dt_w[d*4+2], dtw3 = dt_w[d*4+3];
    const float dtb  = dt_b[d], Dd = Dss[d];
    #pragma unroll 2
    for(int t=0;t<T_LEN;t++){
      const float* db = &s_dbl[t*DBLPAD];
      float4 dt4 = *(const float4*)db;
      float dtv = dtb;
      dtv = fmaf(dt4.x, dtw0, dtv);
      dtv = fmaf(dt4.y, dtw1, dtv);
      dtv = fmaf(dt4.z, dtw2, dtv);
      dtv = fmaf(dt4.w, dtw3, dtv);
      dtv = fmaxf(dtv, 0.f) + log1pf(__expf(-fabsf(dtv)));   // softplus
      float xc = s_xc[t*XCPAD + d];
      float dx = dtv * xc;
      float4 Bv = *(const float4*)&db[4  + sq*4];
      float4 Cv = *(const float4*)&db[20 + sq*4];
      float yp = 0.f;
      hs[0] = fmaf(dx, Bv.x, hs[0]*__expf(dtv*A_d[0])); yp = fmaf(hs[0], Cv.x, yp);
      hs[1] = fmaf(dx, Bv.y, hs[1]*__expf(dtv*A_d[1])); yp = fmaf(hs[1], Cv.y, yp);
      hs[2] = fmaf(dx, Bv.z, hs[2]*__expf(dtv*A_d[2])); yp = fmaf(hs[2], Cv.z, yp);
      hs[3] = fmaf(dx, Bv.w, hs[3]*__expf(dtv*A_d[3])); yp = fmaf(hs[3], Cv.w, yp);
      yp += __shfl_xor(yp, 1, 64);
      yp += __shfl_xor(yp, 2, 64);
      if(sq == 0) s_xc[t*XCPAD + d] = yp + Dd*xc;
    }
  }
  __syncthreads();

  // ---- ph10: u = y * silu(z) (tiling A, both channel halves); stage out_w c-chunk 0
  {
    #pragma unroll
    for(int tt=0;tt<2;tt++){
      float4 y4 = *(const float4*)&s_xc[(tA+tt)*XCPAD + rA];
      float4 zv = zrA[tt];
      float4 u;
      u.x = y4.x * (zv.x / (1.f + __expf(-zv.x)));
      u.y = y4.y * (zv.y / (1.f + __expf(-zv.y)));
      u.z = y4.z * (zv.z / (1.f + __expf(-zv.z)));
      u.w = y4.w * (zv.w / (1.f + __expf(-zv.w)));
      *(float4*)&s_xc[(tA+tt)*XCPAD + rA] = u;
      y4 = *(const float4*)&s_xc[(tA+tt)*XCPAD + 64 + rA];
      zv = zrB[tt];
      u.x = y4.x * (zv.x / (1.f + __expf(-zv.x)));
      u.y = y4.y * (zv.y / (1.f + __expf(-zv.y)));
      u.z = y4.z * (zv.z / (1.f + __expf(-zv.z)));
      u.w = y4.w * (zv.w / (1.f + __expf(-zv.w)));
      *(float4*)&s_xc[(tA+tt)*XCPAD + 64 + rA] = u;
    }
    for(int idx = tid; idx < 4096; idx += 512){   // out_w[:, 0:64] -> sW[c][j]
      int c = idx & 63, j = idx >> 6;
      sW[c*WH + j] = out_w[j*128 + c];
    }
  }
  __syncthreads();

  // ---- ph11/ph13: out = u @ out_w.T (c-chunked, persistent acc) + residual
  {
    float4 a0 = z4, a1 = z4;
    for(int c0=0;c0<64;c0+=4){
      float4 w0 = *(const float4*)&sW[(c0+0)*WH + rA];
      float4 w1 = *(const float4*)&sW[(c0+1)*WH + rA];
      float4 w2 = *(const float4*)&sW[(c0+2)*WH + rA];
      float4 w3 = *(const float4*)&sW[(c0+3)*WH + rA];
      float4 u0 = *(const float4*)&s_xc[(tA+0)*XCPAD + c0];
      float4 u1 = *(const float4*)&s_xc[(tA+1)*XCPAD + c0];
      a0 = f4fma(u0.x,w0,a0); a0 = f4fma(u0.y,w1,a0); a0 = f4fma(u0.z,w2,a0); a0 = f4fma(u0.w,w3,a0);
      a1 = f4fma(u1.x,w0,a1); a1 = f4fma(u1.y,w1,a1); a1 = f4fma(u1.z,w2,a1); a1 = f4fma(u1.w,w3,a1);
    }
    __syncthreads();
    for(int idx = tid; idx < 4096; idx += 512){   // out_w[:, 64:128] -> sW
      int c = idx & 63, j = idx >> 6;
      sW[c*WH + j] = out_w[j*128 + 64 + c];
    }
    __syncthreads();
    for(int c0=0;c0<64;c0+=4){
      float4 w0 = *(const float4*)&sW[(c0+0)*WH + rA];
      float4 w1 = *(const float4*)&sW[(c0+1)*WH + rA];
      float4 w2 = *(const float4*)&sW[(c0+2)*WH + rA];
      float4 w3 = *(const float4*)&sW[(c0+3)*WH + rA];
      float4 u0 = *(const float4*)&s_xc[(tA+0)*XCPAD + 64 + c0];
      float4 u1 = *(const float4*)&s_xc[(tA+1)*XCPAD + 64 + c0];
      a0 = f4fma(u0.x,w0,a0); a0 = f4fma(u0.y,w1,a0); a0 = f4fma(u0.z,w2,a0); a0 = f4fma(u0.w,w3,a0);
      a1 = f4fma(u1.x,w0,a1); a1 = f4fma(u1.y,w1,a1); a1 = f4fma(u1.z,w2,a1); a1 = f4fma(u1.w,w3,a1);
    }
    #pragma unroll
    for(int tt=0;tt<2;tt++){
      float4 a = (tt==0) ? a0 : a1;
      int t = tA + tt;
      size_t tok = (size_t)(b*T_LEN + t)*NODES + n;
      float4 xv = *(const float4*)&x[tok*64 + rA];
      float4 o;
      o.x = xv.x + a.x; o.y = xv.y + a.y; o.z = xv.z + a.z; o.w = xv.w + a.w;
      *(float4*)&xT[tok*64 + rA] = o;
      *(float4*)&s_h[t*HPAD + rA] = o;     // xT tile for the tail
    }
  }

  // ---- ph14: fused K/V/gate projections from the xT tile
  if(do_tail){
    __syncthreads();
    // K and V: 4 dims x 2 tokens per thread, weights broadcast-read from global
    {
      float4 kb4 = *(const float4*)&k_b[rA];
      float4 vb4 = *(const float4*)&v_b[rA];
      float4 ka0 = kb4, ka1 = kb4, va0 = vb4, va1 = vb4;
      for(int c0=0;c0<64;c0+=4){
        float4 x0 = *(const float4*)&s_h[(tA+0)*HPAD + c0];
        float4 x1 = *(const float4*)&s_h[(tA+1)*HPAD + c0];
        float4 w0 = *(const float4*)&k_w[(rA+0)*64 + c0];
        float4 w1 = *(const float4*)&k_w[(rA+1)*64 + c0];
        float4 w2 = *(const float4*)&k_w[(rA+2)*64 + c0];
        float4 w3 = *(const float4*)&k_w[(rA+3)*64 + c0];
        ka0.x = dp4(x0,w0,ka0.x); ka0.y = dp4(x0,w1,ka0.y); ka0.z = dp4(x0,w2,ka0.z); ka0.w = dp4(x0,w3,ka0.w);
        ka1.x = dp4(x1,w0,ka1.x); ka1.y = dp4(x1,w1,ka1.y); ka1.z = dp4(x1,w2,ka1.z); ka1.w = dp4(x1,w3,ka1.w);
        w0 = *(const float4*)&v_w[(rA+0)*64 + c0];
        w1 = *(const float4*)&v_w[(rA+1)*64 + c0];
        w2 = *(const float4*)&v_w[(rA+2)*64 + c0];
        w3 = *(const float4*)&v_w[(rA+3)*64 + c0];
        va0.x = dp4(x0,w0,va0.x); va0.y = dp4(x0,w1,va0.y); va0.z = dp4(x0,w2,va0.z); va0.w = dp4(x0,w3,va0.w);
        va1.x = dp4(x1,w0,va1.x); va1.y = dp4(x1,w1,va1.y); va1.z = dp4(x1,w2,va1.z); va1.w = dp4(x1,w3,va1.w);
      }
      size_t tok0 = (size_t)(b*T_LEN + tA+0)*NODES + n;
      size_t tok1 = (size_t)(b*T_LEN + tA+1)*NODES + n;
      *(float4*)&Kb[tok0*64 + rA] = ka0;
      *(float4*)&Kb[tok1*64 + rA] = ka1;
      *(float4*)&Vb[tok0*64 + rA] = va0;
      *(float4*)&Vb[tok1*64 + rA] = va1;
    }
    // gate: 8 threads per token, 2 g1-rows each
    {
      const int td = tid >> 3;
      const int sr = (tid & 7) * 2;
      float partial = 0.f;
      #pragma unroll
      for(int i=0;i<2;i++){
        int r = sr + i;
        float u = dot64(&s_h[td*HPAD], g1_w + r*64, g1_b[r]);
        u = 0.5f * u * (1.f + erff(u * 0.70710678118654752f));
        partial = fmaf(u, g2_w[r], partial);
      }
      partial += __shfl_xor(partial, 1, 64);
      partial += __shfl_xor(partial, 2, 64);
      partial += __shfl_xor(partial, 4, 64);
      if((tid & 7) == 0){
        size_t tok = (size_t)(b*T_LEN + td)*NODES + n;
        gate[tok] = 1.f / (1.f + __expf(-(partial + g2_b[0])));
      }
    }
  }
}

// ---------------- R9 tile attention (validated, unchanged) ----------------
// grid = NTOK/64 blocks, 256 threads; 64 tokens per block.
__global__ __launch_bounds__(256)
void opt_attn3(const float* __restrict__ xT,
               const float* __restrict__ Kb, const float* __restrict__ Vb,
               const float* __restrict__ gate, const int* __restrict__ nbr,
               const float* __restrict__ q_w, const float* __restrict__ q_b,
               const float* __restrict__ o_w, const float* __restrict__ o_b,
               const float* __restrict__ ln2_g, const float* __restrict__ ln2_b,
               float* __restrict__ out)
{
  __shared__ float s_x[64*68];
  __shared__ float s_q[64*68];
  const int tid = threadIdx.x;
  const size_t tb = (size_t)blockIdx.x * 64;

  for(int i = tid; i < 64*64; i += 256){
    int t = i >> 6, c = i & 63;
    s_x[t*68 + c] = xT[(tb + t)*64 + c];
  }
  __syncthreads();

  {
    const int r0 = (tid & 15) * 4, t0 = (tid >> 4) * 4;
    float4 b4 = *(const float4*)&q_b[r0];
    float4 acc[4];
    #pragma unroll
    for(int tt=0;tt<4;tt++) acc[tt] = b4;
    for(int c0=0;c0<64;c0+=4){
      float4 w0 = *(const float4*)&q_w[(r0+0)*64 + c0];
      float4 w1 = *(const float4*)&q_w[(r0+1)*64 + c0];
      float4 w2 = *(const float4*)&q_w[(r0+2)*64 + c0];
      float4 w3 = *(const float4*)&q_w[(r0+3)*64 + c0];
      #pragma unroll
      for(int tt=0;tt<4;tt++){
        float4 x4 = *(const float4*)&s_x[(t0+tt)*68 + c0];
        acc[tt].x = dp4(x4, w0, acc[tt].x);
        acc[tt].y = dp4(x4, w1, acc[tt].y);
        acc[tt].z = dp4(x4, w2, acc[tt].z);
        acc[tt].w = dp4(x4, w3, acc[tt].w);
      }
    }
    #pragma unroll
    for(int tt=0;tt<4;tt++)
      *(float4*)&s_q[(t0+tt)*68 + r0] = acc[tt];
  }
  __syncthreads();

  const int td = tid >> 2, h = tid & 3;
  const size_t idxg = tb + td;
  const int n  = (int)(idxg % NODES);
  const int bt = (int)(idxg / NODES);

  const float* qp = &s_q[td*68 + h*16];
  float4 q0 = *(const float4*)(qp+0);
  float4 q1 = *(const float4*)(qp+4);
  float4 q2 = *(const float4*)(qp+8);
  float4 q3 = *(const float4*)(qp+12);
  int rows[TOPK];
  #pragma unroll
  for(int k=0;k<TOPK;k++) rows[k] = bt*NODES + nbr[n*TOPK + k];
  __syncthreads();

  float sc[TOPK];
  #pragma unroll
  for(int k=0;k<TOPK;k++){
    const float* kr = &Kb[(size_t)rows[k]*64 + h*16];
    float4 k0 = *(const float4*)(kr+0);
    float4 k1 = *(const float4*)(kr+4);
    float4 k2 = *(const float4*)(kr+8);
    float4 k3 = *(const float4*)(kr+12);
    float s = dp4(q0,k0, dp4(q1,k1, dp4(q2,k2, dp4(q3,k3, 0.f))));
    sc[k] = s * 0.25f;
  }
  float mx = sc[0];
  #pragma unroll
  for(int k=1;k<TOPK;k++) mx = fmaxf(mx, sc[k]);
  float ssum = 0.f;
  #pragma unroll
  for(int k=0;k<TOPK;k++){ sc[k] = __expf(sc[k]-mx); ssum += sc[k]; }
  float inv = 1.f/ssum;
  float4 o0 = make_float4(0.f,0.f,0.f,0.f), o1 = o0, o2 = o0, o3 = o0;
  #pragma unroll
  for(int k=0;k<TOPK;k++){
    const float* vr = &Vb[(size_t)rows[k]*64 + h*16];
    float p = sc[k]*inv;
    o0 = f4fma(p, *(const float4*)(vr+0),  o0);
    o1 = f4fma(p, *(const float4*)(vr+4),  o1);
    o2 = f4fma(p, *(const float4*)(vr+8),  o2);
    o3 = f4fma(p, *(const float4*)(vr+12), o3);
  }
  {
    float* op = &s_q[td*68 + h*16];
    *(float4*)(op+0)  = o0;
    *(float4*)(op+4)  = o1;
    *(float4*)(op+8)  = o2;
    *(float4*)(op+12) = o3;
  }
  __syncthreads();

  float4 ores[4];
  const int r0 = (tid & 15) * 4, t0 = (tid >> 4) * 4;
  {
    float4 b4 = *(const float4*)&o_b[r0];
    float4 acc[4];
    #pragma unroll
    for(int tt=0;tt<4;tt++) acc[tt] = b4;
    for(int c0=0;c0<64;c0+=4){
      float4 w0 = *(const float4*)&o_w[(r0+0)*64 + c0];
      float4 w1 = *(const float4*)&o_w[(r0+1)*64 + c0];
      float4 w2 = *(const float4*)&o_w[(r0+2)*64 + c0];
      float4 w3 = *(const float4*)&o_w[(r0+3)*64 + c0];
      #pragma unroll
      for(int tt=0;tt<4;tt++){
        float4 g4 = *(const float4*)&s_q[(t0+tt)*68 + c0];
        acc[tt].x = dp4(g4, w0, acc[tt].x);
        acc[tt].y = dp4(g4, w1, acc[tt].y);
        acc[tt].z = dp4(g4, w2, acc[tt].z);
        acc[tt].w = dp4(g4, w3, acc[tt].w);
      }
    }
    #pragma unroll
    for(int tt=0;tt<4;tt++){
      float g = gate[tb + t0 + tt];
      float4 xv = *(const float4*)&s_x[(t0+tt)*68 + r0];
      ores[tt].x = xv.x + g*(acc[tt].x - xv.x);
      ores[tt].y = xv.y + g*(acc[tt].y - xv.y);
      ores[tt].z = xv.z + g*(acc[tt].z - xv.z);
      ores[tt].w = xv.w + g*(acc[tt].w - xv.w);
    }
  }
  __syncthreads();
  #pragma unroll
  for(int tt=0;tt<4;tt++)
    *(float4*)&s_q[(t0+tt)*68 + r0] = ores[tt];
  __syncthreads();

  {
    const float* orow = &s_q[td*68 + h*16];
    float4 a0 = *(const float4*)(orow+0);
    float4 a1 = *(const float4*)(orow+4);
    float4 a2 = *(const float4*)(orow+8);
    float4 a3 = *(const float4*)(orow+12);
    float sum = (a0.x+a0.y+a0.z+a0.w) + (a1.x+a1.y+a1.z+a1.w)
              + (a2.x+a2.y+a2.z+a2.w) + (a3.x+a3.y+a3.z+a3.w);
    sum += __shfl_xor(sum, 1, 64);
    sum += __shfl_xor(sum, 2, 64);
    float mean = sum * (1.f/64.f);
    a0.x-=mean; a0.y-=mean; a0.z-=mean; a0.w-=mean;
    a1.x-=mean; a1.y-=mean; a1.z-=mean; a1.w-=mean;
    a2.x-=mean; a2.y-=mean; a2.z-=mean; a2.w-=mean;
    a3.x-=mean; a3.y-=mean; a3.z-=mean; a3.w-=mean;
    float sq = (a0.x*a0.x+a0.y*a0.y+a0.z*a0.z+a0.w*a0.w)
             + (a1.x*a1.x+a1.y*a1.y+a1.z*a1.z+a1.w*a1.w)
             + (a2.x*a2.x+a2.y*a2.y+a2.z*a2.z+a2.w*a2.w)
             + (a3.x*a3.x+a3.y*a3.y+a3.z*a3.z+a3.w*a3.w);
    sq += __shfl_xor(sq, 1, 64);
    sq += __shfl_xor(sq, 2, 64);
    float rstd = rsqrtf(sq*(1.f/64.f) + EPS);
    float4 g0 = *(const float4*)&ln2_g[h*16+0];
    float4 g1 = *(const float4*)&ln2_g[h*16+4];
    float4 g2 = *(const float4*)&ln2_g[h*16+8];
    float4 g3 = *(const float4*)&ln2_g[h*16+12];
    float4 bb0 = *(const float4*)&ln2_b[h*16+0];
    float4 bb1 = *(const float4*)&ln2_b[h*16+4];
    float4 bb2 = *(const float4*)&ln2_b[h*16+8];
    float4 bb3 = *(const float4*)&ln2_b[h*16+12];
    float* po = &out[idxg*64 + h*16];
    float4 r;
    r.x=a0.x*rstd*g0.x+bb0.x; r.y=a0.y*rstd*g0.y+bb0.y; r.z=a0.z*rstd*g0.z+bb0.z; r.w=a0.w*rstd*g0.w+bb0.w;
    *(float4*)(po+0) = r;
    r.x=a1.x*rstd*g1.x+bb1.x; r.y=a1.y*rstd*g1.y+bb1.y; r.z=a1.z*rstd*g1.z+bb1.z; r.w=a1.w*rstd*g1.w+bb1.w;
    *(float4*)(po+4) = r;
    r.x=a2.x*rstd*g2.x+bb2.x; r.y=a2.y*rstd*g2.y+bb2.y; r.z=a2.z*rstd*g2.z+bb2.z; r.w=a2.w*rstd*g2.w+bb2.w;
    *(float4*)(po+8) = r;
    r.x=a3.x*rstd*g3.x+bb3.x; r.y=a3.y*rstd*g3.y+bb3.y; r.z=a3.z*rstd*g3.z+bb3.z; r.w=a3.w*rstd*g3.w+bb3.w;
    *(float4*)(po+12) = r;
  }
}

// ---------------- Fallback fused attn (used only if ws too small) ----------------
__global__ __launch_bounds__(64)
void opt_attn(const float* __restrict__ xT, const int* __restrict__ nbr,
              const float* __restrict__ q_w, const float* __restrict__ q_b,
              const float* __restrict__ k_w, const float* __restrict__ k_b,
              const float* __restrict__ v_w, const float* __restrict__ v_b,
              const float* __restrict__ o_w, const float* __restrict__ o_b,
              const float* __restrict__ g1_w, const float* __restrict__ g1_b,
              const float* __restrict__ g2_w, const float* __restrict__ g2_b,
              const float* __restrict__ ln2_g, const float* __restrict__ ln2_b,
              float* __restrict__ out)
{
  const int idx = blockIdx.x;
  const int n   = idx % NODES;
  const int bt  = idx / NODES;
  const int j   = threadIdx.x;

  __shared__ float s_x[64];
  __shared__ float s_nb[TOPK][64];
  __shared__ float s_og[64];
  __shared__ float s_gate;

  float xv = xT[(size_t)idx*64 + j];
  s_x[j] = xv;
  const int base = bt * NODES;
  #pragma unroll
  for(int k=0;k<TOPK;k++){
    int nb2 = nbr[n*TOPK + k];
    s_nb[k][j] = xT[(size_t)(base + nb2)*64 + j];
  }
  __syncthreads();

  float Qj = dot64(s_x, q_w + j*64, q_b[j]);

  float sc[TOPK], vv[TOPK];
  #pragma unroll
  for(int k=0;k<TOPK;k++){
    float Kk = dot64(s_nb[k], k_w + j*64, k_b[j]);
    vv[k]    = dot64(s_nb[k], v_w + j*64, v_b[j]);
    sc[k]    = groupSum16(Qj * Kk) * 0.25f;
  }
  float m = sc[0];
  #pragma unroll
  for(int k=1;k<TOPK;k++) m = fmaxf(m, sc[k]);
  float ssum = 0.f;
  #pragma unroll
  for(int k=0;k<TOPK;k++){ sc[k] = __expf(sc[k]-m); ssum += sc[k]; }
  float inv = 1.f/ssum;
  float og = 0.f;
  #pragma unroll
  for(int k=0;k<TOPK;k++) og = fmaf(sc[k]*inv, vv[k], og);
  s_og[j] = og;
  __syncthreads();

  float xg = dot64(s_og, o_w + j*64, o_b[j]);

  if(j < 16){
    float u = dot64(s_x, g1_w + j*64, g1_b[j]);
    u = 0.5f * u * (1.f + erff(u * 0.70710678118654752f));
    float contrib = groupSum16(u * g2_w[j]);
    if(j == 0) s_gate = 1.f / (1.f + __expf(-(contrib + g2_b[0])));
  }
  __syncthreads();

  float gg = s_gate;
  float o  = xv + gg * (xg - xv);

  float mm  = waveSum64(o) * (1.f/64.f);
  float c   = o - mm;
  float var = waveSum64(c*c) * (1.f/64.f);
  out[(size_t)idx*64 + j] = c * rsqrtf(var + EPS) * ln2_g[j] + ln2_b[j];
}

extern "C" void kernel_launch(void* const* d_in, const int* in_sizes, int n_in,
                              void* d_out, int out_size, void* d_ws, size_t ws_size,
                              hipStream_t stream)
{
  const float* x      = (const float*)d_in[0];
  const int*   nbr    = (const int*  )d_in[1];
  const float* ln1_g  = (const float*)d_in[2];
  const float* ln1_b  = (const float*)d_in[3];
  const float* in_w   = (const float*)d_in[4];
  const float* conv_w = (const float*)d_in[5];
  const float* conv_b = (const float*)d_in[6];
  const float* xp_w   = (const float*)d_in[7];
  const float* dt_w   = (const float*)d_in[8];
  const float* dt_b   = (const float*)d_in[9];
  const float* A_log  = (const float*)d_in[10];
  const float* Dss    = (const float*)d_in[11];
  const float* out_w  = (const float*)d_in[12];
  const float* q_w    = (const float*)d_in[13];
  const float* q_b    = (const float*)d_in[14];
  const float* k_w    = (const float*)d_in[15];
  const float* k_b    = (const float*)d_in[16];
  const float* v_w    = (const float*)d_in[17];
  const float* v_b    = (const float*)d_in[18];
  const float* o_w    = (const float*)d_in[19];
  const float* o_b    = (const float*)d_in[20];
  const float* g1_w   = (const float*)d_in[21];
  const float* g1_b   = (const float*)d_in[22];
  const float* g2_w   = (const float*)d_in[23];
  const float* g2_b   = (const float*)d_in[24];
  const float* ln2_g  = (const float*)d_in[25];
  const float* ln2_b  = (const float*)d_in[26];

  float* xT   = (float*)d_ws;                 // 42.6 MB
  float* Kb   = xT + NTOK*64;                 // +42.6 MB
  float* Vb   = Kb + NTOK*64;                 // +42.6 MB
  float* gg   = Vb + NTOK*64;                 // +0.67 MB
  float* outp = (float*)d_out;

  const size_t need = (NTOK*64*3 + NTOK) * sizeof(float);   // ~128.5 MB (proven R2/R3)
  const int tail = (ws_size >= need) ? 1 : 0;

  (void)hipFuncSetAttribute(reinterpret_cast<const void*>(opt_mamba),
                            hipFuncAttributeMaxDynamicSharedMemorySize, SMEM_BYTES);

  opt_mamba<<<dim3(B_SZ*NODES), dim3(512), SMEM_BYTES, stream>>>(
      x, ln1_g, ln1_b, in_w, conv_w, conv_b, xp_w, dt_w, dt_b, A_log, Dss, out_w,
      k_w, k_b, v_w, v_b, g1_w, g1_b, g2_w, g2_b,
      xT, Kb, Vb, gg, tail);

  if(tail){
    opt_attn3<<<dim3((unsigned)(NTOK/64)), dim3(256), 0, stream>>>(
        xT, Kb, Vb, gg, nbr, q_w, q_b, o_w, o_b, ln2_g, ln2_b, outp);
  } else {
    opt_attn<<<dim3((unsigned)NTOK), dim3(64), 0, stream>>>(
        xT, nbr, q_w, q_b, k_w, k_b, v_w, v_b, o_w, o_b,
        g1_w, g1_b, g2_w, g2_b, ln2_g, ln2_b, outp);
  }
}